// Round 8
// baseline (512.747 us; speedup 1.0000x reference)
//
#include <hip/hip_runtime.h>
#include <hip/hip_bf16.h>
#include <cstdint>
#include <cstddef>

// D = 64 hardcoded (in_feats == hidden == 64).
// CSR build assumes N <= 131072 (src fits 17 bits; bucket = dst>>8 < 512)
// and E <= 2048*4096 (pscan vals[] capacity).
// g is stored as 4 feature-planes of 32B rows (3.2MB/plane: fits per-XCD L2).

#define BN_SHIFT 8              // 256 nodes per bucket
#define BN 256
#define NBK 512                 // max bucket count
#define PCHUNK 4096             // edges per hist/part block
#define PCAP 16                 // LDS bin capacity (overflow -> direct exact-slot write)
#define BCAP 10240              // build LDS edge capacity (mean 8192; global fallback ok)

static __device__ __forceinline__ uint32_t f32_to_bf16_bits(float f) {
    uint32_t u = __builtin_bit_cast(uint32_t, f);
    u += 0x7fffu + ((u >> 16) & 1u);   // RNE (no NaNs in this problem)
    return u >> 16;
}

static __device__ __forceinline__ float bfhi(uint32_t w) {
    return __builtin_bit_cast(float, w);
}

// In-block exclusive scan of bcnt[0..NBK) -> sbb[0..NBK]; 256 threads, 2 elems each.
static __device__ __forceinline__ void scan_bcnt(const int* __restrict__ bcnt,
                                                 int* sbb, int* ssum) {
    int t = threadIdx.x;
    int c0 = bcnt[2 * t], c1 = bcnt[2 * t + 1];
    int v = c0 + c1;
    ssum[t] = v;
    __syncthreads();
    for (int o = 1; o < 256; o <<= 1) {
        int u = (t >= o) ? ssum[t - o] : 0;
        __syncthreads();
        ssum[t] += u;
        __syncthreads();
    }
    int ex = ssum[t] - v;
    sbb[2 * t] = ex;
    sbb[2 * t + 1] = ex + c0;
    if (t == 255) sbb[NBK] = ex + c0 + c1;   // == E
    __syncthreads();
}

// ---------------------------------------------------------------- hist
__global__ __launch_bounds__(256) void hist_kernel(const int* __restrict__ ei,
                                                   int* __restrict__ pcnt, int E) {
    __shared__ int lc[NBK];
    int tid = threadIdx.x;
    lc[tid] = 0; lc[tid + 256] = 0;
    __syncthreads();

    int e0 = blockIdx.x * PCHUNK;
    int m = min(PCHUNK, E - e0);
    const int* dsts = ei + E + e0;
    if ((((uintptr_t)dsts) & 15) == 0) {
        int m4 = m >> 2;
        for (int t = tid; t < m4; t += 256) {
            int4 d = ((const int4*)dsts)[t];
            atomicAdd(&lc[d.x >> BN_SHIFT], 1);
            atomicAdd(&lc[d.y >> BN_SHIFT], 1);
            atomicAdd(&lc[d.z >> BN_SHIFT], 1);
            atomicAdd(&lc[d.w >> BN_SHIFT], 1);
        }
        for (int i = (m4 << 2) + tid; i < m; i += 256)
            atomicAdd(&lc[dsts[i] >> BN_SHIFT], 1);
    } else {
        for (int i = tid; i < m; i += 256)
            atomicAdd(&lc[dsts[i] >> BN_SHIFT], 1);
    }
    __syncthreads();
    int* row = pcnt + (size_t)blockIdx.x * NBK;
    row[tid] = lc[tid];
    row[tid + 256] = lc[tid + 256];
}

// ---------------------------------------------------------------- pscan
__global__ __launch_bounds__(256) void pscan_kernel(int* __restrict__ pcnt,
                                                    int* __restrict__ bcnt, int PB) {
    __shared__ int ss[256];
    int b = blockIdx.x;
    int tid = threadIdx.x;
    int iper = (PB + 255) >> 8;
    int i0 = tid * iper;
    int i1 = min(PB, i0 + iper);
    int vals[8];
    int s = 0;
    for (int i = i0, k = 0; i < i1; ++i, ++k) {
        vals[k] = pcnt[(size_t)i * NBK + b];
        s += vals[k];
    }
    ss[tid] = s;
    __syncthreads();
    for (int o = 1; o < 256; o <<= 1) {
        int u = (tid >= o) ? ss[tid - o] : 0;
        __syncthreads();
        ss[tid] += u;
        __syncthreads();
    }
    int run = ss[tid] - s;
    for (int i = i0, k = 0; i < i1; ++i, ++k) {
        pcnt[(size_t)i * NBK + b] = run;
        run += vals[k];
    }
    if (tid == 255) bcnt[b] = ss[255];
}

// ---------------------------------------------------------------- partition
__global__ __launch_bounds__(256) void part_kernel(const int* __restrict__ ei,
                                                   const int* __restrict__ bcnt,
                                                   const int* __restrict__ poff,
                                                   uint32_t* __restrict__ stage, int E) {
    __shared__ int sbb[NBK + 1];
    __shared__ int ssum[256];
    __shared__ int cnt[NBK];
    __shared__ int base[NBK];
    __shared__ uint32_t bins[NBK * PCAP];   // 32 KB
    int tid = threadIdx.x;
    scan_bcnt(bcnt, sbb, ssum);

    cnt[tid] = 0; cnt[tid + 256] = 0;
    {
        const int* prow = poff + (size_t)blockIdx.x * NBK;
        base[tid] = sbb[tid] + prow[tid];
        base[tid + 256] = sbb[tid + 256] + prow[tid + 256];
    }
    __syncthreads();

    int e0 = blockIdx.x * PCHUNK;
#pragma unroll
    for (int k = 0; k < PCHUNK / 256; ++k) {
        int e = e0 + (k << 8) + tid;
        if (e < E) {
            int s = ei[e];
            int d = ei[E + e];
            int b = d >> BN_SHIFT;
            uint32_t pack = (uint32_t)s | ((uint32_t)(d & (BN - 1)) << 17);
            int pos = atomicAdd(&cnt[b], 1);
            if (pos < PCAP) bins[b * PCAP + pos] = pack;
            else stage[base[b] + pos] = pack;     // exact slot, race-free
        }
    }
    __syncthreads();

    int wave = tid >> 6, lane = tid & 63;
    int sub = lane >> 4, idx = lane & 15;
    for (int b0 = wave * 4; b0 < NBK; b0 += 16) {
        int b = b0 + sub;
        int c = min(cnt[b], PCAP);
        if (idx < c) stage[base[b] + idx] = bins[b * PCAP + idx];
    }
}

// ---------------------------------------------------------------- build
// Self-loop folded at slot 0; col holds PLANE byte offsets (src*32).
__global__ __launch_bounds__(256) void build_kernel(const uint32_t* __restrict__ stage,
                                                    const int* __restrict__ bcnt,
                                                    int* __restrict__ rowptr,
                                                    float* __restrict__ dis,
                                                    int* __restrict__ col, int n) {
    __shared__ int sbb[NBK + 1];
    __shared__ uint32_t eb[BCAP];            // 40 KB
    __shared__ int cnt[BN];
    __shared__ int off[BN];
    __shared__ int cur[BN];
    __shared__ int ssum[256];
    int tid = threadIdx.x;
    scan_bcnt(bcnt, sbb, ssum);
    int b = blockIdx.x;
    int node0 = b << BN_SHIFT;
    int ebase = sbb[b];
    int ecnt = sbb[b + 1] - ebase;
    int colbase = ebase + node0;

    cnt[tid] = 0;
    cur[tid] = 0;
    __syncthreads();

    bool fits = (ecnt <= BCAP);
    for (int i = tid; i < ecnt; i += 256) {
        uint32_t pk = stage[ebase + i];
        if (fits) eb[i] = pk;
        atomicAdd(&cnt[pk >> 17], 1);
    }
    __syncthreads();

    int c = cnt[tid] + 1;                    // + self slot
    ssum[tid] = c;
    __syncthreads();
    for (int o = 1; o < 256; o <<= 1) {
        int u = (tid >= o) ? ssum[tid - o] : 0;
        __syncthreads();
        ssum[tid] += u;
        __syncthreads();
    }
    int ex = ssum[tid] - c;
    off[tid] = ex;
    int node = node0 + tid;
    if (node <= n) rowptr[node] = colbase + ex;   // single writer per entry
    if (node < n) {
        dis[node] = rsqrtf((float)c);        // c = deg+1 (self)
        col[colbase + ex] = node << 5;       // self edge, plane-row byte offset
    }
    __syncthreads();

    if (fits) {
        for (int i = tid; i < ecnt; i += 256) {
            uint32_t pk = eb[i];
            int doff = pk >> 17;
            int p = atomicAdd(&cur[doff], 1);
            col[colbase + off[doff] + 1 + p] = (int)(pk & 0x1ffff) << 5;
        }
    } else {
        for (int i = tid; i < ecnt; i += 256) {
            uint32_t pk = stage[ebase + i];
            int doff = pk >> 17;
            int p = atomicAdd(&cur[doff], 1);
            col[colbase + off[doff] + 1 + p] = (int)(pk & 0x1ffff) << 5;
        }
    }
}

// ---------------------------------------------------------------- GEMM [N,64]@[64,64]
// MODE 0: out = bf16( (x@W) * dis[row] ) in 4-plane layout (16 feats x 32B rows)
// MODE 1: out = fp32( (x@W) + bias ) dense rows
template <int MODE>
__global__ __launch_bounds__(256) void gemm_kernel(const float* __restrict__ x,
                                                   const float* __restrict__ W,
                                                   const float* __restrict__ dis,
                                                   const float* __restrict__ bias,
                                                   void* __restrict__ out, int n) {
    __shared__ float Wl[64 * 64];
    int t = threadIdx.x;
    {
        const float4* W4 = (const float4*)W;
        float4* Wl4 = (float4*)Wl;
#pragma unroll
        for (int i = 0; i < 4; ++i) Wl4[t + i * 256] = W4[t + i * 256];
    }
    __syncthreads();

    int row = blockIdx.x * 256 + t;
    if (row >= n) return;

    const float4* xr = (const float4*)(x + (size_t)row * 64);
    float4 acc4[16];
#pragma unroll
    for (int p = 0; p < 16; ++p) acc4[p] = make_float4(0.f, 0.f, 0.f, 0.f);

    float4 xq = xr[0];
    for (int k4 = 0; k4 < 16; ++k4) {
        float4 xn = xq;
        if (k4 < 15) xn = xr[k4 + 1];
        float xs[4] = {xq.x, xq.y, xq.z, xq.w};
#pragma unroll
        for (int kk = 0; kk < 4; ++kk) {
            float xk = xs[kk];
            const float4* wr = (const float4*)&Wl[((k4 << 2) + kk) << 6];
#pragma unroll
            for (int j4 = 0; j4 < 16; ++j4) {
                float4 wv = wr[j4];
                acc4[j4].x = fmaf(xk, wv.x, acc4[j4].x);
                acc4[j4].y = fmaf(xk, wv.y, acc4[j4].y);
                acc4[j4].z = fmaf(xk, wv.z, acc4[j4].z);
                acc4[j4].w = fmaf(xk, wv.w, acc4[j4].w);
            }
        }
        xq = xn;
    }

    if (MODE == 0) {
        float s = dis[row];
        char* gp = (char*)out;
        size_t pstr = (size_t)n * 32;        // plane stride (bytes)
#pragma unroll
        for (int q = 0; q < 4; ++q) {
            float4 a0 = acc4[4 * q + 0], a1 = acc4[4 * q + 1];
            float4 a2 = acc4[4 * q + 2], a3 = acc4[4 * q + 3];
            uint4 o0, o1;
            o0.x = (f32_to_bf16_bits(a0.y * s) << 16) | f32_to_bf16_bits(a0.x * s);
            o0.y = (f32_to_bf16_bits(a0.w * s) << 16) | f32_to_bf16_bits(a0.z * s);
            o0.z = (f32_to_bf16_bits(a1.y * s) << 16) | f32_to_bf16_bits(a1.x * s);
            o0.w = (f32_to_bf16_bits(a1.w * s) << 16) | f32_to_bf16_bits(a1.z * s);
            o1.x = (f32_to_bf16_bits(a2.y * s) << 16) | f32_to_bf16_bits(a2.x * s);
            o1.y = (f32_to_bf16_bits(a2.w * s) << 16) | f32_to_bf16_bits(a2.z * s);
            o1.z = (f32_to_bf16_bits(a3.y * s) << 16) | f32_to_bf16_bits(a3.x * s);
            o1.w = (f32_to_bf16_bits(a3.w * s) << 16) | f32_to_bf16_bits(a3.z * s);
            uint4* dst = (uint4*)(gp + q * pstr + (size_t)row * 32);
            dst[0] = o0;
            dst[1] = o1;
        }
    } else {
        const float4* b4 = (const float4*)bias;
        float4* fo = (float4*)out;
#pragma unroll
        for (int p = 0; p < 16; ++p) {
            float4 bb = b4[p];
            float4 a = acc4[p];
            a.x += bb.x; a.y += bb.y; a.z += bb.z; a.w += bb.w;
            fo[(size_t)row * 16 + p] = a;
        }
    }
}

// ---------------------------------------------------------------- pull aggregation (planar)
// blockIdx.y = feature plane (16 feats, 32B rows, 3.2MB: per-XCD-L2-resident).
// Wave per node (4 nodes/wave sequentially): 8 groups x 8 lanes; group = edge,
// lane covers 2 feats (dword). Shuffle-reduce over groups. Self at slot 0.
__global__ __launch_bounds__(256) void agg_kernel(const char* __restrict__ g,
                                                  const int* __restrict__ rowptr,
                                                  const int* __restrict__ col,
                                                  const float* __restrict__ dis,
                                                  const float* __restrict__ bias,
                                                  float* __restrict__ out,
                                                  int n, int pstr) {
    int tid = threadIdx.x;
    int wave = tid >> 6, lane = tid & 63;
    int grp = lane >> 3, chk = lane & 7;
    int q = blockIdx.y;
    const char* gp = g + (size_t)q * pstr + (chk << 2);
    int f = (q << 4) + (chk << 1);
    float b0 = bias[f], b1 = bias[f + 1];

    int nbase = blockIdx.x * 16 + wave * 4;
#pragma unroll
    for (int t = 0; t < 4; ++t) {
        int node = nbase + t;
        if (node >= n) return;

        float ax = 0.f, ay = 0.f;
        int beg = rowptr[node];
        int end = rowptr[node + 1];
        int e = beg + grp;
        for (; e + 8 < end; e += 16) {
            uint32_t w0 = *(const uint32_t*)(gp + col[e]);
            uint32_t w1 = *(const uint32_t*)(gp + col[e + 8]);
            ax += bfhi(w0 << 16); ay += bfhi(w0 & 0xffff0000u);
            ax += bfhi(w1 << 16); ay += bfhi(w1 & 0xffff0000u);
        }
        if (e < end) {
            uint32_t w = *(const uint32_t*)(gp + col[e]);
            ax += bfhi(w << 16); ay += bfhi(w & 0xffff0000u);
        }

#pragma unroll
        for (int m = 8; m < 64; m <<= 1) {
            ax += __shfl_xor(ax, m, 64);
            ay += __shfl_xor(ay, m, 64);
        }

        if (grp == 0) {
            float dv = dis[node];
            float2 o;
            o.x = fmaxf(fmaf(ax, dv, b0), 0.f);
            o.y = fmaxf(fmaf(ay, dv, b1), 0.f);
            *(float2*)(out + (size_t)node * 64 + f) = o;
        }
    }
}

// ---------------------------------------------------------------- launch
extern "C" void kernel_launch(void* const* d_in, const int* in_sizes, int n_in,
                              void* d_out, int out_size, void* d_ws, size_t ws_size,
                              hipStream_t stream) {
    const float* x  = (const float*)d_in[0];
    const int*   ei = (const int*)d_in[1];
    const float* W1 = (const float*)d_in[2];
    const float* b1 = (const float*)d_in[3];
    const float* W2 = (const float*)d_in[4];
    const float* b2 = (const float*)d_in[5];
    // Wq/bq/Wk/bk dead: softmax over a length-1 axis is identity.
    const float* Wv = (const float*)d_in[10];
    const float* bv = (const float*)d_in[11];

    const int N = in_sizes[0] / 64;
    const int E = in_sizes[1] / 2;
    const int NB = (N + BN - 1) >> BN_SHIFT;
    const int PB = (E + PCHUNK - 1) / PCHUNK;

    auto align_up = [](size_t v) { return (v + 255) & ~(size_t)255; };
    char* p = (char*)d_ws;
    int*   rowptr = (int*)p;    p += align_up((size_t)(N + 1) * 4);
    float* dis    = (float*)p;  p += align_up((size_t)N * 4);
    int*   pcnt   = (int*)p;    p += align_up((size_t)PB * NBK * 4);
    int*   bcnt   = (int*)p;    p += align_up((size_t)NBK * 4);
    int*   col    = (int*)p;    p += align_up((size_t)(E + N + BN) * 4);
    size_t gsz    = (size_t)N * 128 > (size_t)E * 4 ? (size_t)N * 128 : (size_t)E * 4;
    char*  gbuf   = p;          p += align_up(gsz);              // 4 planes; stage alias
    float* xbuf   = (float*)p;  p += align_up((size_t)N * 256);  // fp32 hidden
    uint32_t* stage = (uint32_t*)gbuf;   // dead before first gemm writes gbuf

    int nbl = (N + 255) / 256;
    dim3 agrid((N + 15) / 16, 4);       // x: node groups, y: feature plane
    int pstr = N * 32;                  // plane stride bytes

    hist_kernel <<<PB, 256, 0, stream>>>(ei, pcnt, E);
    pscan_kernel<<<NBK, 256, 0, stream>>>(pcnt, bcnt, PB);
    part_kernel <<<PB, 256, 0, stream>>>(ei, bcnt, pcnt, stage, E);
    build_kernel<<<NB, 256, 0, stream>>>(stage, bcnt, rowptr, dis, col, N);

    // layer 1: g = bf16(dis * (x@W1)) planar; xbuf = relu(dis*Agg(g) + b1)
    gemm_kernel<0><<<nbl, 256, 0, stream>>>(x, W1, dis, nullptr, gbuf, N);
    agg_kernel<<<agrid, 256, 0, stream>>>(gbuf, rowptr, col, dis, b1, xbuf, N, pstr);

    // layer 2
    gemm_kernel<0><<<nbl, 256, 0, stream>>>(xbuf, W2, dis, nullptr, gbuf, N);
    agg_kernel<<<agrid, 256, 0, stream>>>(gbuf, rowptr, col, dis, b2, xbuf, N, pstr);

    // output: v = xbuf@Wv + bv (attention identity at seq_len 1)
    gemm_kernel<1><<<nbl, 256, 0, stream>>>(xbuf, Wv, nullptr, bv, d_out, N);
}

// Round 9
// 362.872 us; speedup vs baseline: 1.4130x; 1.4130x over previous
//
#include <hip/hip_runtime.h>
#include <hip/hip_bf16.h>
#include <cstdint>
#include <cstddef>

// D = 64 hardcoded (in_feats == hidden == 64).
// CSR build assumes N <= 131072 (src fits 17 bits; bucket = dst>>8 < 512)
// and E <= 2048*4096 (pscan vals[] capacity).

#define BN_SHIFT 8              // 256 nodes per bucket
#define BN 256
#define NBK 512                 // max bucket count
#define PCHUNK 4096             // edges per hist/part block
#define PCAP 16                 // LDS bin capacity (overflow -> direct exact-slot write)

static __device__ __forceinline__ uint32_t f32_to_bf16_bits(float f) {
    uint32_t u = __builtin_bit_cast(uint32_t, f);
    u += 0x7fffu + ((u >> 16) & 1u);   // RNE (no NaNs in this problem)
    return u >> 16;
}

static __device__ __forceinline__ void add_bf16x8(float* acc, uint4 q) {
    uint32_t w0 = q.x, w1 = q.y, w2 = q.z, w3 = q.w;
    acc[0] += __builtin_bit_cast(float, w0 << 16);
    acc[1] += __builtin_bit_cast(float, w0 & 0xffff0000u);
    acc[2] += __builtin_bit_cast(float, w1 << 16);
    acc[3] += __builtin_bit_cast(float, w1 & 0xffff0000u);
    acc[4] += __builtin_bit_cast(float, w2 << 16);
    acc[5] += __builtin_bit_cast(float, w2 & 0xffff0000u);
    acc[6] += __builtin_bit_cast(float, w3 << 16);
    acc[7] += __builtin_bit_cast(float, w3 & 0xffff0000u);
}

// In-block exclusive scan of bcnt[0..NBK) -> sbb[0..NBK]; 256 threads, 2 elems each.
static __device__ __forceinline__ void scan_bcnt(const int* __restrict__ bcnt,
                                                 int* sbb, int* ssum) {
    int t = threadIdx.x;
    int c0 = bcnt[2 * t], c1 = bcnt[2 * t + 1];
    int v = c0 + c1;
    ssum[t] = v;
    __syncthreads();
    for (int o = 1; o < 256; o <<= 1) {
        int u = (t >= o) ? ssum[t - o] : 0;
        __syncthreads();
        ssum[t] += u;
        __syncthreads();
    }
    int ex = ssum[t] - v;
    sbb[2 * t] = ex;
    sbb[2 * t + 1] = ex + c0;
    if (t == 255) sbb[NBK] = ex + c0 + c1;   // == E
    __syncthreads();
}

// ---------------------------------------------------------------- hist
__global__ __launch_bounds__(256) void hist_kernel(const int* __restrict__ ei,
                                                   int* __restrict__ pcnt, int E) {
    __shared__ int lc[NBK];
    int tid = threadIdx.x;
    lc[tid] = 0; lc[tid + 256] = 0;
    __syncthreads();

    int e0 = blockIdx.x * PCHUNK;
    int m = min(PCHUNK, E - e0);
    const int* dsts = ei + E + e0;
    if ((((uintptr_t)dsts) & 15) == 0) {
        int m4 = m >> 2;
        for (int t = tid; t < m4; t += 256) {
            int4 d = ((const int4*)dsts)[t];
            atomicAdd(&lc[d.x >> BN_SHIFT], 1);
            atomicAdd(&lc[d.y >> BN_SHIFT], 1);
            atomicAdd(&lc[d.z >> BN_SHIFT], 1);
            atomicAdd(&lc[d.w >> BN_SHIFT], 1);
        }
        for (int i = (m4 << 2) + tid; i < m; i += 256)
            atomicAdd(&lc[dsts[i] >> BN_SHIFT], 1);
    } else {
        for (int i = tid; i < m; i += 256)
            atomicAdd(&lc[dsts[i] >> BN_SHIFT], 1);
    }
    __syncthreads();
    int* row = pcnt + (size_t)blockIdx.x * NBK;
    row[tid] = lc[tid];
    row[tid + 256] = lc[tid + 256];
}

// ---------------------------------------------------------------- pscan
__global__ __launch_bounds__(256) void pscan_kernel(int* __restrict__ pcnt,
                                                    int* __restrict__ bcnt, int PB) {
    __shared__ int ss[256];
    int b = blockIdx.x;
    int tid = threadIdx.x;
    int iper = (PB + 255) >> 8;
    int i0 = tid * iper;
    int i1 = min(PB, i0 + iper);
    int vals[8];
    int s = 0;
    for (int i = i0, k = 0; i < i1; ++i, ++k) {
        vals[k] = pcnt[(size_t)i * NBK + b];
        s += vals[k];
    }
    ss[tid] = s;
    __syncthreads();
    for (int o = 1; o < 256; o <<= 1) {
        int u = (tid >= o) ? ss[tid - o] : 0;
        __syncthreads();
        ss[tid] += u;
        __syncthreads();
    }
    int run = ss[tid] - s;
    for (int i = i0, k = 0; i < i1; ++i, ++k) {
        pcnt[(size_t)i * NBK + b] = run;
        run += vals[k];
    }
    if (tid == 255) bcnt[b] = ss[255];
}

// ---------------------------------------------------------------- partition
// Exact-slot: base = sbb(in-block scan of bcnt) + poff[blk][b]. NO global atomics.
__global__ __launch_bounds__(256) void part_kernel(const int* __restrict__ ei,
                                                   const int* __restrict__ bcnt,
                                                   const int* __restrict__ poff,
                                                   uint32_t* __restrict__ stage, int E) {
    __shared__ int sbb[NBK + 1];
    __shared__ int ssum[256];
    __shared__ int cnt[NBK];
    __shared__ int base[NBK];
    __shared__ uint32_t bins[NBK * PCAP];   // 32 KB
    int tid = threadIdx.x;
    scan_bcnt(bcnt, sbb, ssum);

    cnt[tid] = 0; cnt[tid + 256] = 0;
    {
        const int* prow = poff + (size_t)blockIdx.x * NBK;
        base[tid] = sbb[tid] + prow[tid];
        base[tid + 256] = sbb[tid + 256] + prow[tid + 256];
    }
    __syncthreads();

    int e0 = blockIdx.x * PCHUNK;
#pragma unroll
    for (int k = 0; k < PCHUNK / 256; ++k) {
        int e = e0 + (k << 8) + tid;
        if (e < E) {
            int s = ei[e];
            int d = ei[E + e];
            int b = d >> BN_SHIFT;
            uint32_t pack = (uint32_t)s | ((uint32_t)(d & (BN - 1)) << 17);
            int pos = atomicAdd(&cnt[b], 1);
            if (pos < PCAP) bins[b * PCAP + pos] = pack;
            else stage[base[b] + pos] = pack;     // exact slot, race-free
        }
    }
    __syncthreads();

    int wave = tid >> 6, lane = tid & 63;
    int sub = lane >> 4, idx = lane & 15;
    for (int b0 = wave * 4; b0 < NBK; b0 += 16) {
        int b = b0 + sub;
        int c = min(cnt[b], PCAP);
        if (idx < c) stage[base[b] + idx] = bins[b * PCAP + idx];
    }
}

// ---------------------------------------------------------------- build
// One block per bucket, two global passes over its stage slice (2nd is L2-hot).
// Self-loop folded at slot 0; col holds byte offsets (src*128). Low LDS (~6KB).
__global__ __launch_bounds__(256) void build_kernel(const uint32_t* __restrict__ stage,
                                                    const int* __restrict__ bcnt,
                                                    int* __restrict__ rowptr,
                                                    float* __restrict__ dis,
                                                    int* __restrict__ col, int n) {
    __shared__ int sbb[NBK + 1];
    __shared__ int ssum[256];
    __shared__ int cnt[BN];
    __shared__ int off[BN];
    __shared__ int cur[BN];
    int tid = threadIdx.x;
    scan_bcnt(bcnt, sbb, ssum);
    int b = blockIdx.x;
    int node0 = b << BN_SHIFT;
    int ebase = sbb[b];
    int ecnt = sbb[b + 1] - ebase;
    int colbase = ebase + node0;             // prior buckets' edges + self slots

    cnt[tid] = 0;
    cur[tid] = 0;
    __syncthreads();

    for (int i = tid; i < ecnt; i += 256)    // pass 1: per-node counts
        atomicAdd(&cnt[stage[ebase + i] >> 17], 1);
    __syncthreads();

    int c = cnt[tid] + 1;                    // + self slot
    ssum[tid] = c;
    __syncthreads();
    for (int o = 1; o < 256; o <<= 1) {
        int u = (tid >= o) ? ssum[tid - o] : 0;
        __syncthreads();
        ssum[tid] += u;
        __syncthreads();
    }
    int ex = ssum[tid] - c;
    off[tid] = ex;
    int node = node0 + tid;
    if (node <= n) rowptr[node] = colbase + ex;   // single writer per entry
    if (node < n) {
        dis[node] = rsqrtf((float)c);        // c = deg+1 (self)
        col[colbase + ex] = node << 7;       // self edge, byte offset
    }
    __syncthreads();

    for (int i = tid; i < ecnt; i += 256) {  // pass 2: scatter (L2-hot re-read)
        uint32_t pk = stage[ebase + i];
        int doff = pk >> 17;
        int p = atomicAdd(&cur[doff], 1);
        col[colbase + off[doff] + 1 + p] = (int)(pk & 0x1ffff) << 7;
    }
}

// ---------------------------------------------------------------- GEMM [N,64]@[64,64]
// MODE 0: out = bf16( (x@W) * dis[row] ) 128B rows;  MODE 1: out = fp32( (x@W)+bias )
template <int MODE>
__global__ __launch_bounds__(256) void gemm_kernel(const float* __restrict__ x,
                                                   const float* __restrict__ W,
                                                   const float* __restrict__ dis,
                                                   const float* __restrict__ bias,
                                                   void* __restrict__ out, int n) {
    __shared__ float Wl[64 * 64];
    int t = threadIdx.x;
    {
        const float4* W4 = (const float4*)W;
        float4* Wl4 = (float4*)Wl;
#pragma unroll
        for (int i = 0; i < 4; ++i) Wl4[t + i * 256] = W4[t + i * 256];
    }
    __syncthreads();

    int row = blockIdx.x * 256 + t;
    if (row >= n) return;

    const float4* xr = (const float4*)(x + (size_t)row * 64);
    float4 acc4[16];
#pragma unroll
    for (int p = 0; p < 16; ++p) acc4[p] = make_float4(0.f, 0.f, 0.f, 0.f);

    float4 xq = xr[0];
    for (int k4 = 0; k4 < 16; ++k4) {
        float4 xn = xq;
        if (k4 < 15) xn = xr[k4 + 1];
        float xs[4] = {xq.x, xq.y, xq.z, xq.w};
#pragma unroll
        for (int kk = 0; kk < 4; ++kk) {
            float xk = xs[kk];
            const float4* wr = (const float4*)&Wl[((k4 << 2) + kk) << 6];
#pragma unroll
            for (int j4 = 0; j4 < 16; ++j4) {
                float4 wv = wr[j4];
                acc4[j4].x = fmaf(xk, wv.x, acc4[j4].x);
                acc4[j4].y = fmaf(xk, wv.y, acc4[j4].y);
                acc4[j4].z = fmaf(xk, wv.z, acc4[j4].z);
                acc4[j4].w = fmaf(xk, wv.w, acc4[j4].w);
            }
        }
        xq = xn;
    }

    if (MODE == 0) {
        float s = dis[row];
        uint4* go = (uint4*)out;
#pragma unroll
        for (int p = 0; p < 8; ++p) {
            float4 a = acc4[2 * p];
            float4 bq = acc4[2 * p + 1];
            uint4 o;
            o.x = (f32_to_bf16_bits(a.y * s) << 16) | f32_to_bf16_bits(a.x * s);
            o.y = (f32_to_bf16_bits(a.w * s) << 16) | f32_to_bf16_bits(a.z * s);
            o.z = (f32_to_bf16_bits(bq.y * s) << 16) | f32_to_bf16_bits(bq.x * s);
            o.w = (f32_to_bf16_bits(bq.w * s) << 16) | f32_to_bf16_bits(bq.z * s);
            go[(size_t)row * 8 + p] = o;
        }
    } else {
        const float4* b4 = (const float4*)bias;
        float4* fo = (float4*)out;
#pragma unroll
        for (int p = 0; p < 16; ++p) {
            float4 bb = b4[p];
            float4 a = acc4[p];
            a.x += bb.x; a.y += bb.y; a.z += bb.z; a.w += bb.w;
            fo[(size_t)row * 16 + p] = a;
        }
    }
}

// ---------------------------------------------------------------- pull aggregation
// One wave per node (round-5 proven shape): 8 groups x 8 lanes, lane chunk = 16B
// of the 128B bf16 row; col holds byte offsets (src*128), self-loop at slot 0.
// Edge loop unrolled x4 for 4 outstanding gathers per lane.
__global__ __launch_bounds__(256) void agg_kernel(const char* __restrict__ g,
                                                  const int* __restrict__ rowptr,
                                                  const int* __restrict__ col,
                                                  const float* __restrict__ dis,
                                                  const float* __restrict__ bias,
                                                  float* __restrict__ out, int n) {
    int wid = (blockIdx.x * 256 + threadIdx.x) >> 6;
    if (wid >= n) return;
    int lane = threadIdx.x & 63;
    int grp = lane >> 3;
    int chk16 = (lane & 7) << 4;
    const char* gc = g + chk16;

    float acc[8];
#pragma unroll
    for (int j = 0; j < 8; ++j) acc[j] = 0.f;

    int e = rowptr[wid] + grp;
    int end = rowptr[wid + 1];
    for (; e + 24 < end; e += 32) {
        int o0 = col[e];
        int o1 = col[e + 8];
        int o2 = col[e + 16];
        int o3 = col[e + 24];
        uint4 q0 = *(const uint4*)(gc + o0);
        uint4 q1 = *(const uint4*)(gc + o1);
        uint4 q2 = *(const uint4*)(gc + o2);
        uint4 q3 = *(const uint4*)(gc + o3);
        add_bf16x8(acc, q0);
        add_bf16x8(acc, q1);
        add_bf16x8(acc, q2);
        add_bf16x8(acc, q3);
    }
    for (; e < end; e += 8) {
        add_bf16x8(acc, *(const uint4*)(gc + col[e]));
    }

#pragma unroll
    for (int m = 8; m < 64; m <<= 1) {
#pragma unroll
        for (int j = 0; j < 8; ++j) acc[j] += __shfl_xor(acc[j], m, 64);
    }

    if (grp == 0) {
        float dv = dis[wid];
        float4 o0, o1;
        const float* bb = bias + (chk16 >> 1);   // chk*8
        o0.x = fmaxf(fmaf(acc[0], dv, bb[0]), 0.f);
        o0.y = fmaxf(fmaf(acc[1], dv, bb[1]), 0.f);
        o0.z = fmaxf(fmaf(acc[2], dv, bb[2]), 0.f);
        o0.w = fmaxf(fmaf(acc[3], dv, bb[3]), 0.f);
        o1.x = fmaxf(fmaf(acc[4], dv, bb[4]), 0.f);
        o1.y = fmaxf(fmaf(acc[5], dv, bb[5]), 0.f);
        o1.z = fmaxf(fmaf(acc[6], dv, bb[6]), 0.f);
        o1.w = fmaxf(fmaf(acc[7], dv, bb[7]), 0.f);
        float4* fo = (float4*)out;
        fo[(size_t)wid * 16 + (chk16 >> 3) + 0] = o0;   // chk*2
        fo[(size_t)wid * 16 + (chk16 >> 3) + 1] = o1;
    }
}

// ---------------------------------------------------------------- launch
extern "C" void kernel_launch(void* const* d_in, const int* in_sizes, int n_in,
                              void* d_out, int out_size, void* d_ws, size_t ws_size,
                              hipStream_t stream) {
    const float* x  = (const float*)d_in[0];
    const int*   ei = (const int*)d_in[1];
    const float* W1 = (const float*)d_in[2];
    const float* b1 = (const float*)d_in[3];
    const float* W2 = (const float*)d_in[4];
    const float* b2 = (const float*)d_in[5];
    // Wq/bq/Wk/bk dead: softmax over a length-1 axis is identity.
    const float* Wv = (const float*)d_in[10];
    const float* bv = (const float*)d_in[11];

    const int N = in_sizes[0] / 64;
    const int E = in_sizes[1] / 2;
    const int NB = (N + BN - 1) >> BN_SHIFT;
    const int PB = (E + PCHUNK - 1) / PCHUNK;

    auto align_up = [](size_t v) { return (v + 255) & ~(size_t)255; };
    char* p = (char*)d_ws;
    int*   rowptr = (int*)p;    p += align_up((size_t)(N + 1) * 4);
    float* dis    = (float*)p;  p += align_up((size_t)N * 4);
    int*   pcnt   = (int*)p;    p += align_up((size_t)PB * NBK * 4);
    int*   bcnt   = (int*)p;    p += align_up((size_t)NBK * 4);
    int*   col    = (int*)p;    p += align_up((size_t)(E + N + BN) * 4);
    size_t gsz    = (size_t)N * 128 > (size_t)E * 4 ? (size_t)N * 128 : (size_t)E * 4;
    char*  gbuf   = p;          p += align_up(gsz);              // bf16 rows; stage alias
    float* xbuf   = (float*)p;  p += align_up((size_t)N * 256);  // fp32 hidden
    uint32_t* stage = (uint32_t*)gbuf;   // dead before first gemm writes gbuf

    int nbl = (N + 255) / 256;
    int abl = (N + 3) / 4;      // one wave per node, 4 waves/block

    hist_kernel <<<PB, 256, 0, stream>>>(ei, pcnt, E);
    pscan_kernel<<<NBK, 256, 0, stream>>>(pcnt, bcnt, PB);
    part_kernel <<<PB, 256, 0, stream>>>(ei, bcnt, pcnt, stage, E);
    build_kernel<<<NB, 256, 0, stream>>>(stage, bcnt, rowptr, dis, col, N);

    // layer 1: g = bf16(dis * (x@W1)); xbuf = relu(dis*Agg(g) + b1)
    gemm_kernel<0><<<nbl, 256, 0, stream>>>(x, W1, dis, nullptr, gbuf, N);
    agg_kernel<<<abl, 256, 0, stream>>>(gbuf, rowptr, col, dis, b1, xbuf, N);

    // layer 2
    gemm_kernel<0><<<nbl, 256, 0, stream>>>(xbuf, W2, dis, nullptr, gbuf, N);
    agg_kernel<<<abl, 256, 0, stream>>>(gbuf, rowptr, col, dis, b2, xbuf, N);

    // output: v = xbuf@Wv + bv (attention identity at seq_len 1)
    gemm_kernel<1><<<nbl, 256, 0, stream>>>(xbuf, Wv, nullptr, bv, d_out, N);
}